// Round 7
// baseline (534.008 us; speedup 1.0000x reference)
//
#include <hip/hip_runtime.h>
#include <stdint.h>

typedef unsigned short ushort_t;
typedef __attribute__((ext_vector_type(8))) __bf16 bf16x8;
typedef __attribute__((ext_vector_type(4))) float floatx4;
typedef __attribute__((ext_vector_type(8))) unsigned short ushort8v;

// ---------------- constants ----------------
#define TT 8192L   // tokens = B*L
#define LB 4096L   // tokens per batch
#define DD 768L
#define DI 3072L
#define NH 48L
#define R3C 256L
#define R2C 1024L
#define NP 6272L   // padded proj width (2*DI + NH = 6192 -> 49*128)
#define CHS 64L    // scan chunk length (tokens)

// ---------------- helpers ----------------
__device__ __forceinline__ float b2f(ushort_t u) {
  union { unsigned u32; float f; } v; v.u32 = ((unsigned)u) << 16; return v.f;
}
__device__ __forceinline__ ushort_t f2b(float f) {
  union { float f; unsigned u32; } v; v.f = f;
  unsigned r = v.u32 + 0x7FFFu + ((v.u32 >> 16) & 1u);
  return (ushort_t)(r >> 16);
}
__device__ __forceinline__ float fast_tanh(float x) {
  float e = __expf(2.0f * x);
  return 1.0f - 2.0f / (e + 1.0f);
}
// async global->LDS, 16B/lane; LDS base wave-uniform. Only in 4-wave k_gemm.
__device__ __forceinline__ void g2l16(const void* g, void* l) {
  __builtin_amdgcn_global_load_lds(
      (const __attribute__((address_space(1))) unsigned int*)g,
      (__attribute__((address_space(3))) unsigned int*)l, 16, 0, 0);
}

// ---------------- prep: 5 weight transposes (f32->bf16, [K][N]->[N][K]) + RMSNorm1 ----------
// blocks 0..2503 transpose; blocks 2504..10695 rms over 8192 tokens
__global__ __launch_bounds__(256) void k_prep(const float* __restrict__ s0, ushort_t* __restrict__ d0,
                                              const float* __restrict__ s1, ushort_t* __restrict__ d1,
                                              const float* __restrict__ s2, ushort_t* __restrict__ d2,
                                              const float* __restrict__ s3, ushort_t* __restrict__ d3,
                                              const float* __restrict__ s4, ushort_t* __restrict__ d4,
                                              const float* __restrict__ x,
                                              const float* __restrict__ w1,
                                              ushort_t* __restrict__ xn) {
  __shared__ float tile[64][65];
  int id = blockIdx.x;
  if (id < 2504) {
    const float* src; ushort_t* dst; int K, N, gx;
    if (id < 1176)      {            src = s0; dst = d0; K = 768;  N = 6192; gx = 12; }
    else if (id < 1752) { id -= 1176; src = s1; dst = d1; K = 3072; N = 768;  gx = 48; }
    else if (id < 1800) { id -= 1752; src = s2; dst = d2; K = 768;  N = 256;  gx = 12; }
    else if (id < 1992) { id -= 1800; src = s3; dst = d3; K = 1024; N = 768;  gx = 16; }
    else                { id -= 1992; src = s4; dst = d4; K = 2048; N = 1024; gx = 32; }
    int k0 = (id % gx) * 64, n0 = (id / gx) * 64;
    int c = threadIdx.x & 63, r4 = threadIdx.x >> 6;
#pragma unroll
    for (int s = 0; s < 16; s++) {
      int r = s * 4 + r4;
      int n = n0 + c;
      tile[c][r] = (n < N) ? src[(long)(k0 + r) * N + n] : 0.0f;
    }
    __syncthreads();
#pragma unroll
    for (int s = 0; s < 16; s++) {
      int r = s * 4 + r4;
      dst[(long)(n0 + r) * K + k0 + c] = f2b(tile[r][c]);
    }
  } else {
    int t = id - 2504, tid = threadIdx.x;
    int lane = tid & 63, wid = tid >> 6;
    const float* xr = x + (long)t * DD;
    float v0 = xr[tid], v1 = xr[tid + 256], v2 = xr[tid + 512];
    float ss = v0 * v0 + v1 * v1 + v2 * v2;
    for (int o = 32; o; o >>= 1) ss += __shfl_down(ss, o);
    __shared__ float red[4];
    if (lane == 0) red[wid] = ss;
    __syncthreads();
    float tot = red[0] + red[1] + red[2] + red[3];
    float rr = rsqrtf(tot / 768.0f + 1e-5f);
    ushort_t* orow = xn + (long)t * DD;
    orow[tid]       = f2b(v0 * rr * w1[tid]);
    orow[tid + 256] = f2b(v1 * rr * w1[tid + 256]);
    orow[tid + 512] = f2b(v2 * rr * w1[tid + 512]);
  }
}

// ---------------- fused out-proj combine + RMSNorm2 + router (per batch, 4096 blocks) ----------
__global__ __launch_bounds__(256) void k_fuse2(const float* __restrict__ P,   // [4][LB*DD]
                                               const float* __restrict__ x,   // batch offset
                                               const float* __restrict__ ls1,
                                               const float* __restrict__ w2,
                                               const float* __restrict__ wr,  // [768][8]
                                               ushort_t* __restrict__ x1,
                                               ushort_t* __restrict__ x2n,
                                               float* __restrict__ wrt) {
  int t = blockIdx.x, tid = threadIdx.x;
  int lane = tid & 63, wid = tid >> 6;
  int dd[3] = {tid, tid + 256, tid + 512};
  float v[3];
#pragma unroll
  for (int i = 0; i < 3; i++) {
    long ix = (long)t * DD + dd[i];
    float s = P[ix] + P[LB * DD + ix] + P[2 * LB * DD + ix] + P[3 * LB * DD + ix];
    float xv = x[ix] + ls1[dd[i]] * s;
    x1[ix] = f2b(xv);
    v[i] = xv;
  }
  float ss = v[0] * v[0] + v[1] * v[1] + v[2] * v[2];
  for (int o = 32; o; o >>= 1) ss += __shfl_down(ss, o);
  __shared__ float red[4];
  __shared__ float wred[4][8];
  __shared__ float slog[8];
  if (lane == 0) red[wid] = ss;
  __syncthreads();
  float tot = red[0] + red[1] + red[2] + red[3];
  float rr = rsqrtf(tot / 768.0f + 1e-5f);
  float p[8] = {0, 0, 0, 0, 0, 0, 0, 0};
  ushort_t* orow = x2n + (long)t * DD;
#pragma unroll
  for (int i = 0; i < 3; i++) {
    float xnv = v[i] * rr * w2[dd[i]];
    orow[dd[i]] = f2b(xnv);
    const float* wrow = wr + (long)dd[i] * 8;
#pragma unroll
    for (int e = 0; e < 8; e++) p[e] += xnv * wrow[e];
  }
#pragma unroll
  for (int e = 0; e < 8; e++) {
    float s = p[e];
    for (int o = 32; o; o >>= 1) s += __shfl_down(s, o);
    if (lane == 0) wred[wid][e] = s;
  }
  __syncthreads();
  if (tid < 8)
    slog[tid] = (wred[0][tid] + wred[1][tid] + wred[2][tid] + wred[3][tid]) * 2.0f;
  __syncthreads();
  if (tid == 0) {
    float l[8];
#pragma unroll
    for (int e = 0; e < 8; e++) l[e] = slog[e];
    int e0 = 0; float b0 = l[0];
#pragma unroll
    for (int e = 1; e < 8; e++) if (l[e] > b0) { b0 = l[e]; e0 = e; }
    int e1 = -1; float b1 = -1e30f;
#pragma unroll
    for (int e = 0; e < 8; e++) if (e != e0 && l[e] > b1) { b1 = l[e]; e1 = e; }
    float ex = __expf(b1 - b0);
    float pd = 1.0f / (1.0f + ex);
    float* wo = wrt + (long)t * 8;
#pragma unroll
    for (int e = 0; e < 8; e++) wo[e] = 0.0f;
    wo[e0] = pd;
    wo[e1] = ex * pd;
  }
}

// stage one 64-token x 64-dim head-slice tile into LDS via registers.
// lds[tt*64 + dim] == src[tt][dim]
__device__ __forceinline__ void stage_tile(const ushort_t* __restrict__ g, long rowstride,
                                           ushort_t* __restrict__ lds, int lane) {
  const int lrow = lane >> 3;
  const int dcol = (lane & 7) * 8;
#pragma unroll
  for (int c8 = 0; c8 < 8; c8++) {
    ushort8v v = *(const ushort8v*)(g + (long)(c8 * 8 + lrow) * rowstride + dcol);
    *(ushort8v*)&lds[(c8 * 64 + lane) * 8] = v;
  }
}

__device__ __forceinline__ float alpha_of(const ushort_t* __restrict__ proj, int tok, int h,
                                          const float* __restrict__ dtb) {
  float dt = b2f(proj[(long)tok * NP + 2 * DI + h]) + dtb[h];
  float sp = (dt > 20.0f) ? dt : log1pf(__expf(dt));
  return __expf(-sp);
}

// ---------------- scan phase 1: per-chunk (64-token) summaries, 3072 blocks ----------------
__global__ __launch_bounds__(64) void k_scan1(const ushort_t* __restrict__ proj,
                                              const float* __restrict__ dtb,
                                              float* __restrict__ ssum,
                                              float* __restrict__ asum) {
  __shared__ __align__(16) ushort_t u_lds[64 * 64];
  __shared__ float s_alpha[64];
  const int lane = threadIdx.x;
  const int idx = blockIdx.x;          // h*64 + c
  const int c = idx & 63;
  const int h = idx >> 6;
  s_alpha[lane] = alpha_of(proj, (int)(c * CHS) + lane, h, dtb);
  const ushort_t* ug = proj + (long)c * CHS * NP + (long)h * 64;
  stage_tile(ug, NP, u_lds, lane);
  __syncthreads();
  float s = 0.0f, A = 1.0f;
#pragma unroll
  for (int tt = 0; tt < 64; tt++) {
    float a = s_alpha[tt];
    float u = b2f(u_lds[tt * 64 + lane]);
    s = fmaf(a, s, u);
    A *= a;
  }
  ssum[(long)idx * 64 + lane] = s;
  if (lane == 0) asum[idx] = A;
}

// ---------------- scan phase 3: inline chunk carry + scan + silu + scaled tanh -------------
__global__ __launch_bounds__(64) void k_scan3(const ushort_t* __restrict__ proj,
                                              const float* __restrict__ dtb,
                                              const float* __restrict__ ssum,
                                              const float* __restrict__ asum,
                                              ushort_t* __restrict__ y) {
  __shared__ __align__(16) ushort_t u_lds[64 * 64];
  __shared__ __align__(16) ushort_t z_lds[64 * 64];
  __shared__ float s_alpha[64];
  const int lane = threadIdx.x;
  const int idx = blockIdx.x;          // h*64 + c
  const int c = idx & 63;
  const int h = idx >> 6;
  s_alpha[lane] = alpha_of(proj, (int)(c * CHS) + lane, h, dtb);
  const ushort_t* ug = proj + (long)c * CHS * NP + (long)h * 64;
  const ushort_t* zg = ug + DI;
  ushort_t* yg = y + (long)c * CHS * DI + (long)h * 64;
  stage_tile(ug, NP, u_lds, lane);
  stage_tile(zg, NP, z_lds, lane);
  // inline carry: recurrence over chunks < c (loads independent, chain is fma only)
  float hs = 0.0f;
  for (int cc = 0; cc < c; cc++) {
    float A = asum[h * 64 + cc];
    float s = ssum[((long)(h * 64 + cc)) * 64 + lane];
    hs = fmaf(A, hs, s);
  }
  __syncthreads();
#pragma unroll
  for (int tt = 0; tt < 64; tt++) {
    float a = s_alpha[tt];
    float u = b2f(u_lds[tt * 64 + lane]);
    hs = fmaf(a, hs, u);
    float zv = b2f(z_lds[tt * 64 + lane]);
    float sig = 1.0f / (1.0f + __expf(-zv));
    float yv = hs * zv * sig;
    yv = 10.0f * fast_tanh(yv * 0.1f);
    yg[(long)tt * DI + lane] = f2b(yv);
  }
}

// ---------------- fused down-proj combine + tanh + A_big build (8192 blocks) ----------------
// lat[d] = 10*tanh(0.1*sum_z P[t][d]);  abig[t][e*256+d] = wrt[t][e]*lat[d]
__global__ __launch_bounds__(256) void k_moe_in(const float* __restrict__ P,  // [3][TT*R3C]
                                                const float* __restrict__ wrt,
                                                ushort_t* __restrict__ abig) {
  int t = blockIdx.x, d = threadIdx.x;
  __shared__ float sw[8];
  if (d < 8) sw[d] = wrt[(long)t * 8 + d];
  long ix = (long)t * R3C + d;
  float s = P[ix] + P[TT * R3C + ix] + P[2 * TT * R3C + ix];
  __syncthreads();
  float lv = 10.0f * fast_tanh(0.1f * s);
  ushort_t* ab = abig + (long)t * 2048;
#pragma unroll
  for (int e = 0; e < 8; e++) ab[e * 256 + d] = f2b(sw[e] * lv);
}

// ---------------- bf16 GEMM, B^T input, BK=64; MODE 0 epilogue via LDS-repack wide stores ----
// MODE 0: bf16 C = A@B      MODE 4: f32 partial C[z] = A@B over K-slice z
template <int MODE>
__global__ __launch_bounds__(256, 4) void k_gemm(const ushort_t* __restrict__ A,   // [M][kstride]
                                                 const ushort_t* __restrict__ Bt,  // [N][kstride]
                                                 void* __restrict__ Cout, int K, int kstride,
                                                 int ldc, long zoff) {
  __shared__ __align__(16) ushort_t sA[2 * 128 * 32];
  __shared__ __align__(16) ushort_t sB[2 * 128 * 32];
  const int tid = threadIdx.x;
  const int lane = tid & 63, wid = tid >> 6;
  const int lm = lane & 15, q = lane >> 4;
  const int wm = wid >> 1, wn = wid & 1;
  const long row0 = (long)blockIdx.x * 128;
  const long col0 = (long)blockIdx.y * 128;
  const int z = blockIdx.z;
  A += (long)z * K;
  Bt += (long)z * K;

  floatx4 acc[4][4] = {};

  const int trow = tid >> 2;        // 0..63
  const int tcol = (tid & 3) * 8;
  const ushort_t* Ag = A + (row0 + trow) * (long)kstride + tcol;
  const ushort_t* Bg = Bt + (col0 + trow) * (long)kstride + tcol;
  const long rstep = 64L * kstride;

  for (int k0 = 0; k0 < K; k0 += 64) {
#pragma unroll
    for (int kk = 0; kk < 2; kk++)
#pragma unroll
      for (int rh = 0; rh < 2; rh++) {
        g2l16(Ag + rh * rstep + k0 + kk * 32, sA + kk * 4096 + rh * 2048 + wid * 512);
        g2l16(Bg + rh * rstep + k0 + kk * 32, sB + kk * 4096 + rh * 2048 + wid * 512);
      }
    __syncthreads();
#pragma unroll
    for (int kk = 0; kk < 2; kk++) {
      bf16x8 af[4], bfr[4];
#pragma unroll
      for (int i = 0; i < 4; i++)
        af[i] = *(const bf16x8*)(const void*)&sA[kk * 4096 + (wm * 64 + i * 16 + lm) * 32 + q * 8];
#pragma unroll
      for (int j = 0; j < 4; j++)
        bfr[j] = *(const bf16x8*)(const void*)&sB[kk * 4096 + (wn * 64 + j * 16 + lm) * 32 + q * 8];
#pragma unroll
      for (int i = 0; i < 4; i++)
#pragma unroll
        for (int j = 0; j < 4; j++)
          acc[i][j] = __builtin_amdgcn_mfma_f32_16x16x32_bf16(af[i], bfr[j], acc[i][j], 0, 0, 0);
    }
    __syncthreads();
  }

  if (MODE == 0) {
    // per-wave 64x64 bf16 quadrant through LDS (stride 72: 16B-aligned rows, <=4-way wr conflicts)
    // slice: 32 rows x 72 = 2304 ushorts (4608B); waves 0,1 in sA, waves 2,3 in sB
    ushort_t* ep = ((wid & 2) ? sB : sA) + (wid & 1) * 2304;
    ushort_t* Cb = (ushort_t*)Cout;
    const int rr = lane >> 3, cc = (lane & 7) * 8;
    __syncthreads();   // all waves done with sA/sB K-loop contents
#pragma unroll
    for (int p = 0; p < 2; p++) {
#pragma unroll
      for (int i2 = 0; i2 < 2; i2++)
#pragma unroll
        for (int j = 0; j < 4; j++)
#pragma unroll
          for (int r = 0; r < 4; r++)
            ep[(i2 * 16 + q * 4 + r) * 72 + j * 16 + lm] = f2b(acc[p * 2 + i2][j][r]);
      // same-wave aliasing: compiler inserts lgkmcnt waits before dependent reads
#pragma unroll
      for (int s = 0; s < 4; s++) {
        ushort8v vv = *(const ushort8v*)&ep[(s * 8 + rr) * 72 + cc];
        long grow = row0 + wm * 64 + p * 32 + s * 8 + rr;
        *(ushort8v*)&Cb[grow * (long)ldc + col0 + wn * 64 + cc] = vv;
      }
    }
  } else {
#pragma unroll
    for (int i = 0; i < 4; i++) {
#pragma unroll
      for (int r = 0; r < 4; r++) {
        long row = row0 + wm * 64 + i * 16 + q * 4 + r;
#pragma unroll
        for (int j = 0; j < 4; j++) {
          long col = col0 + wn * 64 + j * 16 + lm;
          ((float*)Cout)[(long)z * zoff + row * (long)ldc + col] = acc[i][j][r];
        }
      }
    }
  }
}

// out(f32) = b2f(x1) + ls2 * sum_z P   (up-proj epilogue)
__global__ __launch_bounds__(256) void k_comb_out(const float* __restrict__ P, long zoff, int nz,
                                                  const ushort_t* __restrict__ x1,
                                                  const float* __restrict__ ls,
                                                  float* __restrict__ outp) {
  long i = ((long)blockIdx.x * 256 + threadIdx.x) * 4;
  float s[4] = {0, 0, 0, 0};
  for (int zz = 0; zz < nz; zz++) {
    const float* p = P + (long)zz * zoff + i;
#pragma unroll
    for (int j = 0; j < 4; j++) s[j] += p[j];
  }
  int c = (int)(i % DD);
#pragma unroll
  for (int j = 0; j < 4; j++) outp[i + j] = b2f(x1[i + j]) + ls[c + j] * s[j];
}

// ---------------- workspace layout (bytes), peak ~124.9 MB ----------------
#define OFF_WINT   0L                          // 9,633,792
#define OFF_WOUTT  9633792L                    // 4,718,592
#define OFF_WDNT   14352384L                   // 393,216
#define OFF_WUPT   14745600L                   // 1,572,864
#define OFF_GT     16318464L                   // 4,194,304
#define OFF_X1     20512768L                   // 12,582,912
#define OFF_WRT    33095680L                   // 262,144
#define OFF_SSUM   34144256L                   // 786,432
#define OFF_ASUM   34930688L                   // 12,288
#define OFF_XN     35729408L                   // 12,582,912 (alias x2n)
#define OFF_Y      48312320L                   // 25,165,824 (y / dn-partials / moe)
#define OFF_PROJ   73478144L                   // 51,380,224 (proj / out-partials / abig / up-partials)
#define OFF_X2N    OFF_XN
#define OFF_PART   OFF_PROJ   // out-proj partials 50.3MB (proj dead after scan3)
#define OFF_DPART  OFF_Y      // down-proj partials 25.2MB (y dead after fuse2 b=1)
#define OFF_ABIG   OFF_PROJ   // abig 33.5MB (out-partials dead after fuse2)
#define OFF_MOE    OFF_Y      // moe 16.8MB (dn-partials dead after k_moe_in)
#define OFF_UPART  OFF_PROJ   // up-proj partials 50.3MB (abig dead after moe gemm)
#define WS_NEEDED  124858368L

extern "C" void kernel_launch(void* const* d_in, const int* in_sizes, int n_in,
                              void* d_out, int out_size, void* d_ws, size_t ws_size,
                              hipStream_t stream) {
  const float* x     = (const float*)d_in[0];
  const float* rms1w = (const float*)d_in[1];
  const float* W_in  = (const float*)d_in[2];
  const float* dtb   = (const float*)d_in[3];
  const float* W_out = (const float*)d_in[4];
  const float* ls1   = (const float*)d_in[5];
  const float* rms2w = (const float*)d_in[6];
  const float* W_dn  = (const float*)d_in[7];
  const float* W_rtr = (const float*)d_in[8];
  const float* G     = (const float*)d_in[9];
  const float* W_up  = (const float*)d_in[10];
  const float* ls2   = (const float*)d_in[11];
  if (ws_size < (size_t)WS_NEEDED) return;

  char* ws = (char*)d_ws;
  ushort_t* W_inT  = (ushort_t*)(ws + OFF_WINT);
  ushort_t* W_outT = (ushort_t*)(ws + OFF_WOUTT);
  ushort_t* W_dnT  = (ushort_t*)(ws + OFF_WDNT);
  ushort_t* W_upT  = (ushort_t*)(ws + OFF_WUPT);
  ushort_t* GT     = (ushort_t*)(ws + OFF_GT);
  ushort_t* x1     = (ushort_t*)(ws + OFF_X1);
  float*    wrt    = (float*)(ws + OFF_WRT);
  float*    ssum   = (float*)(ws + OFF_SSUM);
  float*    asum   = (float*)(ws + OFF_ASUM);
  ushort_t* xn     = (ushort_t*)(ws + OFF_XN);
  ushort_t* y      = (ushort_t*)(ws + OFF_Y);
  ushort_t* proj   = (ushort_t*)(ws + OFF_PROJ);
  float*    part   = (float*)(ws + OFF_PART);
  float*    dpart  = (float*)(ws + OFF_DPART);
  ushort_t* abig   = (ushort_t*)(ws + OFF_ABIG);
  ushort_t* moe    = (ushort_t*)(ws + OFF_MOE);
  float*    upart  = (float*)(ws + OFF_UPART);
  ushort_t* x2n    = (ushort_t*)(ws + OFF_X2N);
  float*    outp   = (float*)d_out;

  // transposes + rmsnorm1 in one launch
  k_prep<<<10696, 256, 0, stream>>>(W_in, W_inT, W_out, W_outT, W_dn, W_dnT,
                                    W_up, W_upT, G, GT, x, rms1w, xn);

  for (int b = 0; b < 2; b++) {
    const ushort_t* xnb = xn + (long)b * LB * DD;
    // in-proj: M=4096, N=6272, K=768 (1568 blocks)
    k_gemm<0><<<dim3(32, 49, 1), 256, 0, stream>>>(xnb, W_inT, proj, 768, 768, (int)NP, 0);
    k_scan1<<<3072, 64, 0, stream>>>(proj, dtb, ssum, asum);
    k_scan3<<<3072, 64, 0, stream>>>(proj, dtb, ssum, asum, y);
    // out-proj split-K z=4: M=4096, N=768, K=3072 -> 768 blocks (partials alias dead proj)
    k_gemm<4><<<dim3(32, 6, 4), 256, 0, stream>>>(y, W_outT, part, 768, 3072, 768, LB * DD);
    // fused combine + rmsnorm2 + router
    k_fuse2<<<4096, 256, 0, stream>>>(part, x + (long)b * LB * DD, ls1, rms2w, W_rtr,
                                      x1 + (long)b * LB * DD, x2n + (long)b * LB * DD,
                                      wrt + (long)b * LB * 8);
  }

  // down-proj split-K z=3: M=8192, N=256, K=768 -> 384 blocks (partials alias dead y)
  k_gemm<4><<<dim3(64, 2, 3), 256, 0, stream>>>(x2n, W_dnT, dpart, 256, 768, 256, TT * R3C);
  // fused combine + tanh + abig build (abig aliases dead out-partials/proj)
  k_moe_in<<<8192, 256, 0, stream>>>(dpart, wrt, abig);
  // MoE: M=8192, N=1024, K=2048 (512 blocks); moe aliases dead dn-partials
  k_gemm<0><<<dim3(64, 8, 1), 256, 0, stream>>>(abig, GT, moe, 2048, 2048, 1024, 0);
  // up-proj split-K z=2: M=8192, N=768, K=1024 -> 768 blocks (partials alias dead abig)
  k_gemm<4><<<dim3(64, 6, 2), 256, 0, stream>>>(moe, W_upT, upart, 512, 1024, 768, TT * DD);
  k_comb_out<<<6144, 256, 0, stream>>>(upart, TT * DD, 2, x1, ls2, outp);
}

// Round 8
// 495.660 us; speedup vs baseline: 1.0774x; 1.0774x over previous
//
#include <hip/hip_runtime.h>
#include <stdint.h>

typedef unsigned short ushort_t;
typedef __attribute__((ext_vector_type(8))) __bf16 bf16x8;
typedef __attribute__((ext_vector_type(4))) float floatx4;
typedef __attribute__((ext_vector_type(4))) unsigned short ushort4v;
typedef __attribute__((ext_vector_type(8))) unsigned short ushort8v;

// ---------------- constants ----------------
#define TT 8192L   // tokens = B*L
#define LB 4096L   // tokens per batch
#define DD 768L
#define DI 3072L
#define NH 48L
#define R3C 256L
#define R2C 1024L
#define NP 6272L   // padded proj width (2*DI + NH = 6192 -> 49*128)
#define CHS 64L    // scan chunk length (tokens)

// ---------------- helpers ----------------
__device__ __forceinline__ float b2f(ushort_t u) {
  union { unsigned u32; float f; } v; v.u32 = ((unsigned)u) << 16; return v.f;
}
__device__ __forceinline__ ushort_t f2b(float f) {
  union { float f; unsigned u32; } v; v.f = f;
  unsigned r = v.u32 + 0x7FFFu + ((v.u32 >> 16) & 1u);
  return (ushort_t)(r >> 16);
}
__device__ __forceinline__ float fast_tanh(float x) {
  float e = __expf(2.0f * x);
  return 1.0f - 2.0f / (e + 1.0f);
}
// async global->LDS, 16B/lane; LDS base wave-uniform. Only in 4-wave k_gemm.
__device__ __forceinline__ void g2l16(const void* g, void* l) {
  __builtin_amdgcn_global_load_lds(
      (const __attribute__((address_space(1))) unsigned int*)g,
      (__attribute__((address_space(3))) unsigned int*)l, 16, 0, 0);
}

// ---------------- prep: 5 weight transposes (f32->bf16, [K][N]->[N][K]) + RMSNorm1 ----------
__global__ __launch_bounds__(256) void k_prep(const float* __restrict__ s0, ushort_t* __restrict__ d0,
                                              const float* __restrict__ s1, ushort_t* __restrict__ d1,
                                              const float* __restrict__ s2, ushort_t* __restrict__ d2,
                                              const float* __restrict__ s3, ushort_t* __restrict__ d3,
                                              const float* __restrict__ s4, ushort_t* __restrict__ d4,
                                              const float* __restrict__ x,
                                              const float* __restrict__ w1,
                                              ushort_t* __restrict__ xn) {
  __shared__ float tile[64][65];
  int id = blockIdx.x;
  if (id < 2504) {
    const float* src; ushort_t* dst; int K, N, gx;
    if (id < 1176)      {            src = s0; dst = d0; K = 768;  N = 6192; gx = 12; }
    else if (id < 1752) { id -= 1176; src = s1; dst = d1; K = 3072; N = 768;  gx = 48; }
    else if (id < 1800) { id -= 1752; src = s2; dst = d2; K = 768;  N = 256;  gx = 12; }
    else if (id < 1992) { id -= 1800; src = s3; dst = d3; K = 1024; N = 768;  gx = 16; }
    else                { id -= 1992; src = s4; dst = d4; K = 2048; N = 1024; gx = 32; }
    int k0 = (id % gx) * 64, n0 = (id / gx) * 64;
    int c = threadIdx.x & 63, r4 = threadIdx.x >> 6;
#pragma unroll
    for (int s = 0; s < 16; s++) {
      int r = s * 4 + r4;
      int n = n0 + c;
      tile[c][r] = (n < N) ? src[(long)(k0 + r) * N + n] : 0.0f;
    }
    __syncthreads();
#pragma unroll
    for (int s = 0; s < 16; s++) {
      int r = s * 4 + r4;
      dst[(long)(n0 + r) * K + k0 + c] = f2b(tile[r][c]);
    }
  } else {
    int t = id - 2504, tid = threadIdx.x;
    int lane = tid & 63, wid = tid >> 6;
    const float* xr = x + (long)t * DD;
    float v0 = xr[tid], v1 = xr[tid + 256], v2 = xr[tid + 512];
    float ss = v0 * v0 + v1 * v1 + v2 * v2;
    for (int o = 32; o; o >>= 1) ss += __shfl_down(ss, o);
    __shared__ float red[4];
    if (lane == 0) red[wid] = ss;
    __syncthreads();
    float tot = red[0] + red[1] + red[2] + red[3];
    float rr = rsqrtf(tot / 768.0f + 1e-5f);
    ushort_t* orow = xn + (long)t * DD;
    orow[tid]       = f2b(v0 * rr * w1[tid]);
    orow[tid + 256] = f2b(v1 * rr * w1[tid + 256]);
    orow[tid + 512] = f2b(v2 * rr * w1[tid + 512]);
  }
}

// ---------------- fused out-proj combine (bf16 partials) + RMSNorm2 + router ----------------
__global__ __launch_bounds__(256) void k_fuse2(const ushort_t* __restrict__ P,  // [4][LB*DD] bf16
                                               const float* __restrict__ x,     // batch offset
                                               const float* __restrict__ ls1,
                                               const float* __restrict__ w2,
                                               const float* __restrict__ wr,    // [768][8]
                                               ushort_t* __restrict__ x1,
                                               ushort_t* __restrict__ x2n,
                                               float* __restrict__ wrt) {
  int t = blockIdx.x, tid = threadIdx.x;
  int lane = tid & 63, wid = tid >> 6;
  int dd[3] = {tid, tid + 256, tid + 512};
  float v[3];
#pragma unroll
  for (int i = 0; i < 3; i++) {
    long ix = (long)t * DD + dd[i];
    float s = b2f(P[ix]) + b2f(P[LB * DD + ix]) + b2f(P[2 * LB * DD + ix]) + b2f(P[3 * LB * DD + ix]);
    float xv = x[ix] + ls1[dd[i]] * s;
    x1[ix] = f2b(xv);
    v[i] = xv;
  }
  float ss = v[0] * v[0] + v[1] * v[1] + v[2] * v[2];
  for (int o = 32; o; o >>= 1) ss += __shfl_down(ss, o);
  __shared__ float red[4];
  __shared__ float wred[4][8];
  __shared__ float slog[8];
  if (lane == 0) red[wid] = ss;
  __syncthreads();
  float tot = red[0] + red[1] + red[2] + red[3];
  float rr = rsqrtf(tot / 768.0f + 1e-5f);
  float p[8] = {0, 0, 0, 0, 0, 0, 0, 0};
  ushort_t* orow = x2n + (long)t * DD;
#pragma unroll
  for (int i = 0; i < 3; i++) {
    float xnv = v[i] * rr * w2[dd[i]];
    orow[dd[i]] = f2b(xnv);
    const float* wrow = wr + (long)dd[i] * 8;
#pragma unroll
    for (int e = 0; e < 8; e++) p[e] += xnv * wrow[e];
  }
#pragma unroll
  for (int e = 0; e < 8; e++) {
    float s = p[e];
    for (int o = 32; o; o >>= 1) s += __shfl_down(s, o);
    if (lane == 0) wred[wid][e] = s;
  }
  __syncthreads();
  if (tid < 8)
    slog[tid] = (wred[0][tid] + wred[1][tid] + wred[2][tid] + wred[3][tid]) * 2.0f;
  __syncthreads();
  if (tid == 0) {
    float l[8];
#pragma unroll
    for (int e = 0; e < 8; e++) l[e] = slog[e];
    int e0 = 0; float b0 = l[0];
#pragma unroll
    for (int e = 1; e < 8; e++) if (l[e] > b0) { b0 = l[e]; e0 = e; }
    int e1 = -1; float b1 = -1e30f;
#pragma unroll
    for (int e = 0; e < 8; e++) if (e != e0 && l[e] > b1) { b1 = l[e]; e1 = e; }
    float ex = __expf(b1 - b0);
    float pd = 1.0f / (1.0f + ex);
    float* wo = wrt + (long)t * 8;
#pragma unroll
    for (int e = 0; e < 8; e++) wo[e] = 0.0f;
    wo[e0] = pd;
    wo[e1] = ex * pd;
  }
}

// stage one 64-token x 64-dim head-slice tile into LDS via registers.
__device__ __forceinline__ void stage_tile(const ushort_t* __restrict__ g, long rowstride,
                                           ushort_t* __restrict__ lds, int lane) {
  const int lrow = lane >> 3;
  const int dcol = (lane & 7) * 8;
#pragma unroll
  for (int c8 = 0; c8 < 8; c8++) {
    ushort8v v = *(const ushort8v*)(g + (long)(c8 * 8 + lrow) * rowstride + dcol);
    *(ushort8v*)&lds[(c8 * 64 + lane) * 8] = v;
  }
}

__device__ __forceinline__ float alpha_of(const ushort_t* __restrict__ proj, int tok, int h,
                                          const float* __restrict__ dtb) {
  float dt = b2f(proj[(long)tok * NP + 2 * DI + h]) + dtb[h];
  float sp = (dt > 20.0f) ? dt : log1pf(__expf(dt));
  return __expf(-sp);
}

// ---------------- scan phase 1: per-chunk (64-token) summaries, 3072 blocks ----------------
__global__ __launch_bounds__(64) void k_scan1(const ushort_t* __restrict__ proj,
                                              const float* __restrict__ dtb,
                                              float* __restrict__ ssum,
                                              float* __restrict__ asum) {
  __shared__ __align__(16) ushort_t u_lds[64 * 64];
  __shared__ float s_alpha[64];
  const int lane = threadIdx.x;
  const int idx = blockIdx.x;          // h*64 + c
  const int c = idx & 63;
  const int h = idx >> 6;
  s_alpha[lane] = alpha_of(proj, (int)(c * CHS) + lane, h, dtb);
  const ushort_t* ug = proj + (long)c * CHS * NP + (long)h * 64;
  stage_tile(ug, NP, u_lds, lane);
  __syncthreads();
  float s = 0.0f, A = 1.0f;
#pragma unroll
  for (int tt = 0; tt < 64; tt++) {
    float a = s_alpha[tt];
    float u = b2f(u_lds[tt * 64 + lane]);
    s = fmaf(a, s, u);
    A *= a;
  }
  ssum[(long)idx * 64 + lane] = s;
  if (lane == 0) asum[idx] = A;
}

// ---------------- scan phase 2: chunk carries (48 blocks, 64-step serial) ----------------
__global__ __launch_bounds__(64) void k_scan2(const float* __restrict__ ssum,
                                              const float* __restrict__ asum,
                                              float* __restrict__ carry) {
  int h = blockIdx.x, lane = threadIdx.x;
  float cv = 0.0f;
  for (int c = 0; c < 64; c++) {
    carry[((long)h * 64 + c) * 64 + lane] = cv;
    float A = asum[h * 64 + c];
    float s = ssum[((long)h * 64 + c) * 64 + lane];
    cv = A * cv + s;
  }
}

// ---------------- scan phase 3: scan + silu gate + scaled tanh, 3072 blocks ----------------
__global__ __launch_bounds__(64) void k_scan3(const ushort_t* __restrict__ proj,
                                              const float* __restrict__ dtb,
                                              const float* __restrict__ carry,
                                              ushort_t* __restrict__ y) {
  __shared__ __align__(16) ushort_t u_lds[64 * 64];
  __shared__ __align__(16) ushort_t z_lds[64 * 64];
  __shared__ float s_alpha[64];
  const int lane = threadIdx.x;
  const int idx = blockIdx.x;          // h*64 + c
  const int c = idx & 63;
  const int h = idx >> 6;
  s_alpha[lane] = alpha_of(proj, (int)(c * CHS) + lane, h, dtb);
  const ushort_t* ug = proj + (long)c * CHS * NP + (long)h * 64;
  const ushort_t* zg = ug + DI;
  ushort_t* yg = y + (long)c * CHS * DI + (long)h * 64;
  stage_tile(ug, NP, u_lds, lane);
  stage_tile(zg, NP, z_lds, lane);
  __syncthreads();
  float hs = carry[(long)idx * 64 + lane];
#pragma unroll
  for (int tt = 0; tt < 64; tt++) {
    float a = s_alpha[tt];
    float u = b2f(u_lds[tt * 64 + lane]);
    hs = fmaf(a, hs, u);
    float zv = b2f(z_lds[tt * 64 + lane]);
    float sig = 1.0f / (1.0f + __expf(-zv));
    float yv = hs * zv * sig;
    yv = 10.0f * fast_tanh(yv * 0.1f);
    yg[(long)tt * DI + lane] = f2b(yv);
  }
}

// ---------------- fused down-proj combine (bf16 partials) + tanh + A_big build ----------------
__global__ __launch_bounds__(256) void k_moe_in(const ushort_t* __restrict__ P,  // [3][TT*R3C]
                                                const float* __restrict__ wrt,
                                                ushort_t* __restrict__ abig) {
  int t = blockIdx.x, d = threadIdx.x;
  __shared__ float sw[8];
  if (d < 8) sw[d] = wrt[(long)t * 8 + d];
  long ix = (long)t * R3C + d;
  float s = b2f(P[ix]) + b2f(P[TT * R3C + ix]) + b2f(P[2 * TT * R3C + ix]);
  __syncthreads();
  float lv = 10.0f * fast_tanh(0.1f * s);
  ushort_t* ab = abig + (long)t * 2048;
#pragma unroll
  for (int e = 0; e < 8; e++) ab[e * 256 + d] = f2b(sw[e] * lv);
}

// ---------------- bf16 GEMM, B^T input, BK=64, bf16 output w/ LDS-repack wide stores --------
// C + z*zoff gets bf16 A@B over K-slice z (z=0/zoff=0 for plain GEMM)
__global__ __launch_bounds__(256, 4) void k_gemm(const ushort_t* __restrict__ A,   // [M][kstride]
                                                 const ushort_t* __restrict__ Bt,  // [N][kstride]
                                                 ushort_t* __restrict__ C, int K, int kstride,
                                                 int ldc, long zoff) {
  __shared__ __align__(16) ushort_t sA[2 * 128 * 32];
  __shared__ __align__(16) ushort_t sB[2 * 128 * 32];
  const int tid = threadIdx.x;
  const int lane = tid & 63, wid = tid >> 6;
  const int lm = lane & 15, q = lane >> 4;
  const int wm = wid >> 1, wn = wid & 1;
  const long row0 = (long)blockIdx.x * 128;
  const long col0 = (long)blockIdx.y * 128;
  const int z = blockIdx.z;
  A += (long)z * K;
  Bt += (long)z * K;

  floatx4 acc[4][4] = {};

  const int trow = tid >> 2;        // 0..63
  const int tcol = (tid & 3) * 8;
  const ushort_t* Ag = A + (row0 + trow) * (long)kstride + tcol;
  const ushort_t* Bg = Bt + (col0 + trow) * (long)kstride + tcol;
  const long rstep = 64L * kstride;

  for (int k0 = 0; k0 < K; k0 += 64) {
#pragma unroll
    for (int kk = 0; kk < 2; kk++)
#pragma unroll
      for (int rh = 0; rh < 2; rh++) {
        g2l16(Ag + rh * rstep + k0 + kk * 32, sA + kk * 4096 + rh * 2048 + wid * 512);
        g2l16(Bg + rh * rstep + k0 + kk * 32, sB + kk * 4096 + rh * 2048 + wid * 512);
      }
    __syncthreads();
#pragma unroll
    for (int kk = 0; kk < 2; kk++) {
      bf16x8 af[4], bfr[4];
#pragma unroll
      for (int i = 0; i < 4; i++)
        af[i] = *(const bf16x8*)(const void*)&sA[kk * 4096 + (wm * 64 + i * 16 + lm) * 32 + q * 8];
#pragma unroll
      for (int j = 0; j < 4; j++)
        bfr[j] = *(const bf16x8*)(const void*)&sB[kk * 4096 + (wn * 64 + j * 16 + lm) * 32 + q * 8];
#pragma unroll
      for (int i = 0; i < 4; i++)
#pragma unroll
        for (int j = 0; j < 4; j++)
          acc[i][j] = __builtin_amdgcn_mfma_f32_16x16x32_bf16(af[i], bfr[j], acc[i][j], 0, 0, 0);
    }
    __syncthreads();
  }

  // per-wave 64x64 bf16 quadrant through LDS (stride 72), then 16B global stores
  ushort_t* ep = ((wid & 2) ? sB : sA) + (wid & 1) * 2304;
  ushort_t* Cb = C + (long)z * zoff;
  const int rr = lane >> 3, cc = (lane & 7) * 8;
  __syncthreads();   // all waves done with K-loop LDS contents
#pragma unroll
  for (int p = 0; p < 2; p++) {
#pragma unroll
    for (int i2 = 0; i2 < 2; i2++)
#pragma unroll
      for (int j = 0; j < 4; j++)
#pragma unroll
        for (int r = 0; r < 4; r++)
          ep[(i2 * 16 + q * 4 + r) * 72 + j * 16 + lm] = f2b(acc[p * 2 + i2][j][r]);
#pragma unroll
    for (int s = 0; s < 4; s++) {
      ushort8v vv = *(const ushort8v*)&ep[(s * 8 + rr) * 72 + cc];
      long grow = row0 + wm * 64 + p * 32 + s * 8 + rr;
      *(ushort8v*)&Cb[grow * (long)ldc + col0 + wn * 64 + cc] = vv;
    }
  }
}

// out(f32) = b2f(x1) + ls2 * sum_z P (bf16 partials)
__global__ __launch_bounds__(256) void k_comb_out(const ushort_t* __restrict__ P, long zoff, int nz,
                                                  const ushort_t* __restrict__ x1,
                                                  const float* __restrict__ ls,
                                                  float* __restrict__ outp) {
  long i = ((long)blockIdx.x * 256 + threadIdx.x) * 4;
  float s[4] = {0, 0, 0, 0};
  for (int zz = 0; zz < nz; zz++) {
    ushort4v pv = *(const ushort4v*)(P + (long)zz * zoff + i);
    s[0] += b2f(pv.x); s[1] += b2f(pv.y); s[2] += b2f(pv.z); s[3] += b2f(pv.w);
  }
  int c = (int)(i % DD);
#pragma unroll
  for (int j = 0; j < 4; j++) outp[i + j] = b2f(x1[i + j]) + ls[c + j] * s[j];
}

// ---------------- workspace layout (bytes), peak ~124.9 MB ----------------
#define OFF_WINT   0L                          // 9,633,792
#define OFF_WOUTT  9633792L                    // 4,718,592
#define OFF_WDNT   14352384L                   // 393,216
#define OFF_WUPT   14745600L                   // 1,572,864
#define OFF_GT     16318464L                   // 4,194,304
#define OFF_X1     20512768L                   // 12,582,912
#define OFF_WRT    33095680L                   // 262,144
#define OFF_SSUM   34144256L                   // 786,432
#define OFF_ASUM   34930688L                   // 12,288
#define OFF_CARRY  34942976L                   // 786,432
#define OFF_XN     35729408L                   // 12,582,912 (alias x2n)
#define OFF_Y      48312320L                   // 25,165,824 (y / dn-partials(12.6M) / moe(16.8M))
#define OFF_PROJ   73478144L                   // 51,380,224 (proj / out-partials(25.2M) / abig(33.6M) / up-partials(25.2M))
#define OFF_X2N    OFF_XN
#define OFF_PART   OFF_PROJ
#define OFF_DPART  OFF_Y
#define OFF_ABIG   OFF_PROJ
#define OFF_MOE    OFF_Y
#define OFF_UPART  OFF_PROJ
#define WS_NEEDED  124858368L

extern "C" void kernel_launch(void* const* d_in, const int* in_sizes, int n_in,
                              void* d_out, int out_size, void* d_ws, size_t ws_size,
                              hipStream_t stream) {
  const float* x     = (const float*)d_in[0];
  const float* rms1w = (const float*)d_in[1];
  const float* W_in  = (const float*)d_in[2];
  const float* dtb   = (const float*)d_in[3];
  const float* W_out = (const float*)d_in[4];
  const float* ls1   = (const float*)d_in[5];
  const float* rms2w = (const float*)d_in[6];
  const float* W_dn  = (const float*)d_in[7];
  const float* W_rtr = (const float*)d_in[8];
  const float* G     = (const float*)d_in[9];
  const float* W_up  = (const float*)d_in[10];
  const float* ls2   = (const float*)d_in[11];
  if (ws_size < (size_t)WS_NEEDED) return;

  char* ws = (char*)d_ws;
  ushort_t* W_inT  = (ushort_t*)(ws + OFF_WINT);
  ushort_t* W_outT = (ushort_t*)(ws + OFF_WOUTT);
  ushort_t* W_dnT  = (ushort_t*)(ws + OFF_WDNT);
  ushort_t* W_upT  = (ushort_t*)(ws + OFF_WUPT);
  ushort_t* GT     = (ushort_t*)(ws + OFF_GT);
  ushort_t* x1     = (ushort_t*)(ws + OFF_X1);
  float*    wrt    = (float*)(ws + OFF_WRT);
  float*    ssum   = (float*)(ws + OFF_SSUM);
  float*    asum   = (float*)(ws + OFF_ASUM);
  float*    carry  = (float*)(ws + OFF_CARRY);
  ushort_t* xn     = (ushort_t*)(ws + OFF_XN);
  ushort_t* y      = (ushort_t*)(ws + OFF_Y);
  ushort_t* proj   = (ushort_t*)(ws + OFF_PROJ);
  ushort_t* part   = (ushort_t*)(ws + OFF_PART);
  ushort_t* dpart  = (ushort_t*)(ws + OFF_DPART);
  ushort_t* abig   = (ushort_t*)(ws + OFF_ABIG);
  ushort_t* moe    = (ushort_t*)(ws + OFF_MOE);
  ushort_t* upart  = (ushort_t*)(ws + OFF_UPART);
  ushort_t* x2n    = (ushort_t*)(ws + OFF_X2N);
  float*    outp   = (float*)d_out;

  // transposes + rmsnorm1 in one launch
  k_prep<<<10696, 256, 0, stream>>>(W_in, W_inT, W_out, W_outT, W_dn, W_dnT,
                                    W_up, W_upT, G, GT, x, rms1w, xn);

  for (int b = 0; b < 2; b++) {
    const ushort_t* xnb = xn + (long)b * LB * DD;
    // in-proj: M=4096, N=6272, K=768 (1568 blocks)
    k_gemm<<<dim3(32, 49, 1), 256, 0, stream>>>(xnb, W_inT, proj, 768, 768, (int)NP, 0);
    k_scan1<<<3072, 64, 0, stream>>>(proj, dtb, ssum, asum);
    k_scan2<<<48, 64, 0, stream>>>(ssum, asum, carry);
    k_scan3<<<3072, 64, 0, stream>>>(proj, dtb, carry, y);
    // out-proj split-K z=4 (bf16 partials alias dead proj): M=4096, N=768, K=3072
    k_gemm<<<dim3(32, 6, 4), 256, 0, stream>>>(y, W_outT, part, 768, 3072, 768, LB * DD);
    k_fuse2<<<4096, 256, 0, stream>>>(part, x + (long)b * LB * DD, ls1, rms2w, W_rtr,
                                      x1 + (long)b * LB * DD, x2n + (long)b * LB * DD,
                                      wrt + (long)b * LB * 8);
  }

  // down-proj split-K z=3 (bf16 partials alias dead y): M=8192, N=256, K=768
  k_gemm<<<dim3(64, 2, 3), 256, 0, stream>>>(x2n, W_dnT, dpart, 256, 768, 256, TT * R3C);
  k_moe_in<<<8192, 256, 0, stream>>>(dpart, wrt, abig);
  // MoE: M=8192, N=1024, K=2048 (512 blocks); moe aliases dead dn-partials
  k_gemm<<<dim3(64, 8, 1), 256, 0, stream>>>(abig, GT, moe, 2048, 2048, 1024, 0);
  // up-proj split-K z=2 (bf16 partials alias dead abig): M=8192, N=768, K=1024
  k_gemm<<<dim3(64, 6, 2), 256, 0, stream>>>(moe, W_upT, upart, 512, 1024, 768, TT * DD);
  k_comb_out<<<6144, 256, 0, stream>>>(upart, TT * DD, 2, x1, ls2, outp);
}